// Round 16
// baseline (355.757 us; speedup 1.0000x reference)
//
#include <hip/hip_runtime.h>
#include <hip/hip_fp16.h>

// 2-layer GCN via CSR gather built by a two-level counting sort with
// fixed-capacity (padded) coarse buckets. Kernels:
//   k_init_gcur, k_partition, k_bucket, k_gemm1, k_gather1, k_gather2.
// R8: per-edge fp32 LDS atomic accumulation ~6x slower than sorted-gather.
// R10 (counters): nt-store on SCATTERED 4B writes defeats L2 write-combining
// (148MB HBM for 13MB array). Two-level sort exists for the same reason.
// R11/R15: gather1 lane-width {8x4B,4x8B,2x16B} is a DON'T-CARE — coalescer
// merges same-row lane loads; gather is request-count x latency bound.
// R18 (305.5 w/ 4x g1): t_g1_warm + o ~= 29.9us.
// R19 (316.6 w/ 3x sort): t_sort_warm + 3o ~= 50.4us.
// R20 (230.35 w/ 9x init + 1-pass bucket): 14.45 = Δbucket + 8(o+t_init) ->
//   o ~= 1us even if Δbucket=0. LAUNCH OVERHEAD IS DEAD as a lever (~6us
//   total); cooperative fusion EV-negative. Identity now forces
//   t_gemm1 + t_g2 + cold-deltas ~= 133us vs ~35 modeled -> either a kernel
//   is 3-4x slower than modeled OR ~90us is cold-HBM first-touch (harness
//   re-poisons 268MB/iter, L3 flushed).
// R25 (this round): dual replication anchored to the MEASURED 230.35 config
//   (launcher otherwise identical): +3x gemm1, +3x gather2 ->
//   3(t_gemm1+t_g2+2o) = dur - 230.35.
//   Tree: dur 330-390 -> kernels fine, missing mass is cold-HBM ->
//   single-pass sort (kill edge re-read + ebuf round-trip) next;
//   dur >=450 -> a kernel is structurally slow -> isolate which next.
//   Replicas >41us would enter top-5 with full counters = free diagnosis.

#define CB 8                  // coarse bucket = col >> CB (256 nodes/bucket)
#define CAP 9216              // max edges per bucket (mean 8192 + 11 sigma)
#define TILE 4096             // edges per partition block (512 thr x 8)

__global__ void k_init_gcur(int* __restrict__ gcur, int nb) {
    int b = blockIdx.x * blockDim.x + threadIdx.x;
    if (b < nb) gcur[b] = b * CAP;
}

// Pack (col&255)<<17 | row  (row < 2^17).
__global__ void __launch_bounds__(512) k_partition(
        const int* __restrict__ row, const int* __restrict__ col,
        int* __restrict__ gcur, int* __restrict__ ebuf, int e, int nb) {
    __shared__ int hist[512];            // counts -> local cursor
    __shared__ int lbase[512];           // exclusive scan (local base)
    __shared__ int gdelta[512];          // gbase[b] - lbase[b]
    __shared__ int sval[TILE];           // tile sorted by bucket
    __shared__ unsigned short sbkt[TILE];
    const int base = blockIdx.x * TILE;
    const int cnt = min(TILE, e - base);
    const int t = threadIdx.x;
    hist[t] = 0;
    __syncthreads();
#pragma unroll
    for (int k = 0; k < TILE / 512; ++k) {
        int i = base + (k << 9) + t;
        if (i < e) atomicAdd(&hist[col[i] >> CB], 1);
    }
    __syncthreads();
    int v = hist[t];
    lbase[t] = v;
    __syncthreads();
    for (int off = 1; off < 512; off <<= 1) {
        int add = (t >= off) ? lbase[t - off] : 0;
        __syncthreads();
        lbase[t] += add;
        __syncthreads();
    }
    int excl = lbase[t] - v;
    __syncthreads();
    lbase[t] = excl;
    int gb = v ? atomicAdd(&gcur[t], v) : 0;   // t >= nb has v == 0
    gdelta[t] = gb - excl;
    hist[t] = excl;                            // local rank cursor
    __syncthreads();
#pragma unroll
    for (int k = 0; k < TILE / 512; ++k) {
        int i = base + (k << 9) + t;
        if (i < e) {
            int c = col[i], r = row[i];
            int b = c >> CB;
            int p = atomicAdd(&hist[b], 1);
            sval[p] = ((c & ((1 << CB) - 1)) << 17) | r;
            sbkt[p] = (unsigned short)b;
        }
    }
    __syncthreads();
    for (int j = t; j < cnt; j += 512) {       // coalesced emit
        int b = sbkt[j];
        int p = gdelta[b] + j;                 // == gbase[b] + (j - lbase[b])
        if (p < (b + 1) * CAP) ebuf[p] = sval[j];  // overflow guard
    }
}

// One block per bucket, 1024 threads: stage edges into LDS once, recording
// per-edge rank with a SINGLE atomic pass; scan; place with plain reads.
__global__ void __launch_bounds__(1024) k_bucket(
        const int* __restrict__ ebuf, const int* __restrict__ gcur,
        int* __restrict__ begA, int* __restrict__ endA, int* __restrict__ ssrc,
        float* __restrict__ dis, int n) {
    __shared__ int ev[CAP];                 // 36 KB staged bucket
    __shared__ unsigned short srank[CAP];   // 18 KB per-edge rank (R20)
    __shared__ int hist[256];
    __shared__ int sc[256];
    const int b = blockIdx.x, t = threadIdx.x;
    const int base = b * CAP;
    const int cnt = min(gcur[b] - base, CAP);
    if (t < 256) hist[t] = 0;
    __syncthreads();
    for (int j = t; j < cnt; j += 1024) {
        int v = ebuf[base + j];
        ev[j] = v;
        srank[j] = (unsigned short)atomicAdd(&hist[v >> 17], 1);
    }
    __syncthreads();
    int v = 0;
    if (t < 256) { v = hist[t]; sc[t] = v; }
    __syncthreads();
    for (int off = 1; off < 256; off <<= 1) {
        int add = 0;
        if (t < 256 && t >= off) add = sc[t - off];
        __syncthreads();
        if (t < 256) sc[t] += add;
        __syncthreads();
    }
    if (t < 256) {
        int excl = sc[t] - v;
        int node = (b << CB) + t;
        if (node < n) {
            begA[node] = base + excl;
            endA[node] = base + excl + v;
            dis[node] = rsqrtf((float)(v + 1));
        }
        hist[t] = excl;  // exclusive base, read-only below
    }
    __syncthreads();
    for (int j = t; j < cnt; j += 1024) {
        int val = ev[j];
        ssrc[base + hist[val >> 17] + srank[j]] = val & 0x1FFFF;  // no atomics
    }
}

// g[N,16] (fp16) = dis[row] * (x[N,128] @ W1[128,16]).
// 8 lanes/row: coalesced float4 reads, butterfly reduce, 32B coalesced store.
__global__ void k_gemm1(const float* __restrict__ x, const float* __restrict__ W1,
                        const float* __restrict__ dis, __half* __restrict__ gh, int n) {
    __shared__ float wt[16 * 128];
    for (int t = threadIdx.x; t < 2048; t += blockDim.x) {
        int j = t >> 7, k = t & 127;
        wt[t] = W1[k * 16 + j];
    }
    __syncthreads();
    int t = blockIdx.x * blockDim.x + threadIdx.x;
    if (t >= n * 8) return;
    int r = t >> 3, l = t & 7;
    const float4* x4 = (const float4*)x;
    const float4* w4 = (const float4*)wt;
    float4 va = x4[(size_t)r * 32 + l];
    float4 vb = x4[(size_t)r * 32 + l + 8];
    float4 vc = x4[(size_t)r * 32 + l + 16];
    float4 vd = x4[(size_t)r * 32 + l + 24];
    float acc[16];
#pragma unroll
    for (int j = 0; j < 16; ++j) {
        float4 wa = w4[j * 32 + l];
        float4 wb = w4[j * 32 + l + 8];
        float4 wc = w4[j * 32 + l + 16];
        float4 wd = w4[j * 32 + l + 24];
        acc[j] = va.x * wa.x + va.y * wa.y + va.z * wa.z + va.w * wa.w
               + vb.x * wb.x + vb.y * wb.y + vb.z * wb.z + vb.w * wb.w
               + vc.x * wc.x + vc.y * wc.y + vc.z * wc.z + vc.w * wc.w
               + vd.x * wd.x + vd.y * wd.y + vd.z * wd.z + vd.w * wd.w;
    }
#pragma unroll
    for (int j = 0; j < 16; ++j) {
#pragma unroll
        for (int m = 4; m >= 1; m >>= 1) acc[j] += __shfl_xor(acc[j], m, 8);
    }
    float d = dis[r];
    __half2 hh = __floats2half2_rn(d * acc[2 * l], d * acc[2 * l + 1]);
    ((__half2*)gh)[(size_t)r * 8 + l] = hh;  // 8 lanes -> 32B coalesced
}

// Unpack a 16B load (4x half2 = 8 fp16) and accumulate into 8 fp32 lanes.
__device__ inline void h8acc(float4 r, float* a) {
    const __half2* h = (const __half2*)&r;
#pragma unroll
    for (int k = 0; k < 4; ++k) {
        float2 f = __half22float2(h[k]);
        a[2 * k] += f.x;
        a[2 * k + 1] += f.y;
    }
}

// 2 threads/node, 16B (float4 = 8 fp16) reads. Width is a measured don't-care
// (R11/R15); kept at 16B.
__global__ void k_gather1(const int* __restrict__ begA, const int* __restrict__ endA,
                          const int* __restrict__ ssrc,
                          const float4* __restrict__ g8, const float* __restrict__ dis,
                          const float* __restrict__ b1, const float* __restrict__ W2,
                          float* __restrict__ tbuf, int n) {
    int t = blockIdx.x * blockDim.x + threadIdx.x;
    if (t >= n * 2) return;
    int i = t >> 1, l = t & 1;
    float di = dis[i];
    int beg = begA[i], end = endA[i];
    float a[8], b[8];                           // features 8l .. 8l+7
    {
        float4 s = g8[(size_t)i * 2 + l];       // self-loop
        const __half2* h = (const __half2*)&s;
#pragma unroll
        for (int k = 0; k < 4; ++k) {
            float2 f = __half22float2(h[k]);
            a[2 * k] = f.x;
            a[2 * k + 1] = f.y;
            b[2 * k] = 0.f;
            b[2 * k + 1] = 0.f;
        }
    }
    int e = beg;
    for (; e + 8 <= end; e += 8) {
        int s0 = ssrc[e + 0], s1 = ssrc[e + 1], s2 = ssrc[e + 2], s3 = ssrc[e + 3];
        int s4 = ssrc[e + 4], s5 = ssrc[e + 5], s6 = ssrc[e + 6], s7 = ssrc[e + 7];
        float4 r0 = g8[(size_t)s0 * 2 + l];
        float4 r1 = g8[(size_t)s1 * 2 + l];
        float4 r2 = g8[(size_t)s2 * 2 + l];
        float4 r3 = g8[(size_t)s3 * 2 + l];
        float4 r4 = g8[(size_t)s4 * 2 + l];
        float4 r5 = g8[(size_t)s5 * 2 + l];
        float4 r6 = g8[(size_t)s6 * 2 + l];
        float4 r7 = g8[(size_t)s7 * 2 + l];
        h8acc(r0, a); h8acc(r1, b);
        h8acc(r2, a); h8acc(r3, b);
        h8acc(r4, a); h8acc(r5, b);
        h8acc(r6, a); h8acc(r7, b);
    }
    for (; e < end; ++e) {
        float4 r = g8[(size_t)ssrc[e] * 2 + l];
        h8acc(r, a);
    }
    int f = l * 8;
    float u = 0.f;
#pragma unroll
    for (int k = 0; k < 8; ++k)
        u += fmaxf(di * (a[k] + b[k]) + b1[f + k], 0.f) * W2[f + k];
    u += __shfl_xor(u, 1, 2);
    if (l == 0) tbuf[i] = di * u;
}

// 8 threads/node, lane-strided edges (coalesced ssrc), unroll x4 for MLP:
// out[i] = dis[i] * (sum_e t[src] + t[i]) + b2
__global__ void k_gather2(const int* __restrict__ begA, const int* __restrict__ endA,
                          const int* __restrict__ ssrc,
                          const float* __restrict__ tbuf, const float* __restrict__ dis,
                          const float* __restrict__ b2, float* __restrict__ out, int n) {
    int t = blockIdx.x * blockDim.x + threadIdx.x;
    if (t >= n * 8) return;
    int i = t >> 3, l = t & 7;
    int beg = begA[i], end = endA[i];
    float acc = (l == 0) ? tbuf[i] : 0.f;
    float acc1 = 0.f;
    int e = beg + l;
    for (; e + 24 < end; e += 32) {
        int s0 = ssrc[e], s1 = ssrc[e + 8], s2 = ssrc[e + 16], s3 = ssrc[e + 24];
        float v0 = tbuf[s0], v1 = tbuf[s1], v2 = tbuf[s2], v3 = tbuf[s3];
        acc += v0; acc1 += v1; acc += v2; acc1 += v3;
    }
    for (; e < end; e += 8) acc += tbuf[ssrc[e]];
    acc += acc1;
#pragma unroll
    for (int m = 4; m >= 1; m >>= 1) acc += __shfl_xor(acc, m, 8);
    if (l == 0) out[i] = dis[i] * acc + b2[0];
}

extern "C" void kernel_launch(void* const* d_in, const int* in_sizes, int n_in,
                              void* d_out, int out_size, void* d_ws, size_t ws_size,
                              hipStream_t stream) {
    const float* x  = (const float*)d_in[0];
    const int*   ei = (const int*)d_in[1];
    const float* W1 = (const float*)d_in[2];
    const float* b1 = (const float*)d_in[3];
    const float* W2 = (const float*)d_in[4];
    const float* b2 = (const float*)d_in[5];
    float* out = (float*)d_out;

    const int N = in_sizes[0] / 128;   // 100000
    const int E = in_sizes[1] / 2;     // 3200000
    const int* row = ei;        // edge_index[0] = source
    const int* col = ei + E;    // edge_index[1] = target
    const int NB = (N + 255) >> CB;    // coarse buckets (391)
    const size_t PADE = (size_t)NB * CAP;  // padded edge capacity

    // workspace (4B units): ebuf[PADE] (aliased by gh fp16 after k_bucket) |
    // ssrc[PADE] | dis[N] | tbuf[N] | begA[N] | endA[N] | gcur[512]
    size_t bigsz = PADE > (size_t)N * 8 ? PADE : (size_t)N * 8;
    int*    ebuf = (int*)d_ws;
    __half* gh   = (__half*)d_ws;      // aliases ebuf (dead before k_gemm1)
    int*    ssrc = (int*)d_ws + bigsz;
    float*  dis  = (float*)(ssrc + PADE);
    float*  tbuf = dis + N;
    int*    begA = (int*)(tbuf + N);
    int*    endA = begA + N;
    int*    gcur = endA + N;

    auto cdiv = [](int a, int b) { return (a + b - 1) / b; };

    // R20 config (measured 230.35) kept EXACTLY, so the new replicas anchor
    // to it: 3(t_gemm1 + t_g2 + 2o) = dur - 230.35.
    for (int rep = 0; rep < 9; ++rep)
        k_init_gcur<<<cdiv(NB, 256), 256,  0, stream>>>(gcur, NB);
    k_partition<<<cdiv(E, TILE),    512,  0, stream>>>(row, col, gcur, ebuf, E, NB);
    k_bucket   <<<NB,               1024, 0, stream>>>(ebuf, gcur, begA, endA, ssrc, dis, N);
    // R25 instrumentation: gemm1 x4 (idempotent; gh from immutable x/W1/dis).
    k_gemm1    <<<cdiv(N * 8, 256), 256,  0, stream>>>(x, W1, dis, gh, N);
    k_gemm1    <<<cdiv(N * 8, 256), 256,  0, stream>>>(x, W1, dis, gh, N);
    k_gemm1    <<<cdiv(N * 8, 256), 256,  0, stream>>>(x, W1, dis, gh, N);
    k_gemm1    <<<cdiv(N * 8, 256), 256,  0, stream>>>(x, W1, dis, gh, N);
    k_gather1  <<<cdiv(N * 2, 256), 256,  0, stream>>>(begA, endA, ssrc, (const float4*)gh,
                                                       dis, b1, W2, tbuf, N);
    // R25 instrumentation: gather2 x4 (idempotent; out from stable tbuf/CSR).
    k_gather2  <<<cdiv(N * 8, 256), 256,  0, stream>>>(begA, endA, ssrc, tbuf, dis, b2, out, N);
    k_gather2  <<<cdiv(N * 8, 256), 256,  0, stream>>>(begA, endA, ssrc, tbuf, dis, b2, out, N);
    k_gather2  <<<cdiv(N * 8, 256), 256,  0, stream>>>(begA, endA, ssrc, tbuf, dis, b2, out, N);
    k_gather2  <<<cdiv(N * 8, 256), 256,  0, stream>>>(begA, endA, ssrc, tbuf, dis, b2, out, N);
}

// Round 17
// 215.443 us; speedup vs baseline: 1.6513x; 1.6513x over previous
//
#include <hip/hip_runtime.h>
#include <hip/hip_fp16.h>

// 2-layer GCN via CSR gather built by a two-level counting sort with
// fixed-capacity (padded) coarse buckets. Kernels:
//   k_init_gcur, k_partition, k_bucket(+fused gemm1), k_gather1, k_gather2.
// R8: per-edge fp32 LDS atomic accumulation ~6x slower than sorted-gather.
// R10 (counters): nt-store on SCATTERED 4B writes defeats L2 write-combining.
// R11/R15: gather1 lane-width is a DON'T-CARE (coalescer merges same-row
// lane loads); gathers are request-count x latency bound.
// R18/R19/R20/R25 (replica instrumentation, all measured):
//   o ~= 1us/launch (dead lever); warm costs: sort 47, g1 29, gemm1+g2 40
//   (split ~12/28). Warm sum ~122 vs baseline ~216 -> ~90us is COLD-CACHE
//   excess: harness poison-fills 6x268MB between iters, flushing L3; the
//   ei (25.6MB) and x (51.2MB) cold streams sit in SERIAL kernels.
// R26 (this round): FUSE gemm1 into k_bucket. Block b owns nodes
//   [b*256,(b+1)*256) and just computed their dis -> compute their gh rows
//   in-block (131KB coalesced x-read/block), overlapping the cold x-stream
//   with other blocks' LDS-bound sort phases. gh UN-ALIASED from ebuf
//   (in-kernel write would clobber other blocks' unread ebuf). LDS 65KB ->
//   still 2 blocks/CU. Clean 5-launch pipeline, no instrumentation.
//   Predict 195-205. Tree: >=215 -> fusion hurt (VGPR/occupancy), revert
//   fusion keep 1-pass bucket; ~195 -> next target g2 (28us) or sort.

#define CB 8                  // coarse bucket = col >> CB (256 nodes/bucket)
#define CAP 9216              // max edges per bucket (mean 8192 + 11 sigma)
#define TILE 4096             // edges per partition block (512 thr x 8)

__global__ void k_init_gcur(int* __restrict__ gcur, int nb) {
    int b = blockIdx.x * blockDim.x + threadIdx.x;
    if (b < nb) gcur[b] = b * CAP;
}

// Pack (col&255)<<17 | row  (row < 2^17).
__global__ void __launch_bounds__(512) k_partition(
        const int* __restrict__ row, const int* __restrict__ col,
        int* __restrict__ gcur, int* __restrict__ ebuf, int e, int nb) {
    __shared__ int hist[512];            // counts -> local cursor
    __shared__ int lbase[512];           // exclusive scan (local base)
    __shared__ int gdelta[512];          // gbase[b] - lbase[b]
    __shared__ int sval[TILE];           // tile sorted by bucket
    __shared__ unsigned short sbkt[TILE];
    const int base = blockIdx.x * TILE;
    const int cnt = min(TILE, e - base);
    const int t = threadIdx.x;
    hist[t] = 0;
    __syncthreads();
#pragma unroll
    for (int k = 0; k < TILE / 512; ++k) {
        int i = base + (k << 9) + t;
        if (i < e) atomicAdd(&hist[col[i] >> CB], 1);
    }
    __syncthreads();
    int v = hist[t];
    lbase[t] = v;
    __syncthreads();
    for (int off = 1; off < 512; off <<= 1) {
        int add = (t >= off) ? lbase[t - off] : 0;
        __syncthreads();
        lbase[t] += add;
        __syncthreads();
    }
    int excl = lbase[t] - v;
    __syncthreads();
    lbase[t] = excl;
    int gb = v ? atomicAdd(&gcur[t], v) : 0;   // t >= nb has v == 0
    gdelta[t] = gb - excl;
    hist[t] = excl;                            // local rank cursor
    __syncthreads();
#pragma unroll
    for (int k = 0; k < TILE / 512; ++k) {
        int i = base + (k << 9) + t;
        if (i < e) {
            int c = col[i], r = row[i];
            int b = c >> CB;
            int p = atomicAdd(&hist[b], 1);
            sval[p] = ((c & ((1 << CB) - 1)) << 17) | r;
            sbkt[p] = (unsigned short)b;
        }
    }
    __syncthreads();
    for (int j = t; j < cnt; j += 512) {       // coalesced emit
        int b = sbkt[j];
        int p = gdelta[b] + j;                 // == gbase[b] + (j - lbase[b])
        if (p < (b + 1) * CAP) ebuf[p] = sval[j];  // overflow guard
    }
}

// One block per bucket, 1024 threads. Phase A (sort): stage edges into LDS,
// single-atomic-pass rank, scan, place with plain reads -> ssrc/beg/end/dis.
// Phase B (fused gemm1): gh rows for this block's 256 nodes —
// g[node,16] = fp16(dis[node] * (x[node,:] @ W1)), dis read from LDS.
__global__ void __launch_bounds__(1024) k_bucket(
        const int* __restrict__ ebuf, const int* __restrict__ gcur,
        int* __restrict__ begA, int* __restrict__ endA, int* __restrict__ ssrc,
        float* __restrict__ dis,
        const float* __restrict__ x, const float* __restrict__ W1,
        __half* __restrict__ gh, int n) {
    __shared__ int ev[CAP];                 // 36 KB staged bucket
    __shared__ unsigned short srank[CAP];   // 18 KB per-edge rank
    __shared__ int hist[256];
    __shared__ int sc[256];
    __shared__ float sdis[256];             // dis for this block's nodes
    __shared__ float wt[16 * 128];          // 8 KB W1 transposed
    const int b = blockIdx.x, t = threadIdx.x;
    const int base = b * CAP;
    const int cnt = min(gcur[b] - base, CAP);
    if (t < 256) hist[t] = 0;
    // stage W1 (transposed) while hist zeroing
    {
        int j = t >> 7, k = t & 127;            // elems t and t+1024
        wt[t] = W1[k * 16 + j];
        int j2 = (t + 1024) >> 7, k2 = t & 127;
        wt[t + 1024] = W1[k2 * 16 + j2];
    }
    __syncthreads();
    for (int j = t; j < cnt; j += 1024) {
        int v = ebuf[base + j];
        ev[j] = v;
        srank[j] = (unsigned short)atomicAdd(&hist[v >> 17], 1);
    }
    __syncthreads();
    int v = 0;
    if (t < 256) { v = hist[t]; sc[t] = v; }
    __syncthreads();
    for (int off = 1; off < 256; off <<= 1) {
        int add = 0;
        if (t < 256 && t >= off) add = sc[t - off];
        __syncthreads();
        if (t < 256) sc[t] += add;
        __syncthreads();
    }
    if (t < 256) {
        int excl = sc[t] - v;
        int node = (b << CB) + t;
        float d = rsqrtf((float)(v + 1));
        sdis[t] = d;
        if (node < n) {
            begA[node] = base + excl;
            endA[node] = base + excl + v;
            dis[node] = d;
        }
        hist[t] = excl;  // exclusive base, read-only below
    }
    __syncthreads();
    // Phase A finish: place (plain reads, no atomics)
    for (int j = t; j < cnt; j += 1024) {
        int val = ev[j];
        ssrc[base + hist[val >> 17] + srank[j]] = val & 0x1FFFF;
    }
    // Phase B: fused gemm1 for nodes [b<<8, b<<8+256). 8 lanes/row,
    // 128 rows/pass x 2 passes. Coalesced x float4 reads; wt/sdis from LDS.
    const float4* x4 = (const float4*)x;
    const float4* w4 = (const float4*)wt;
    int l = t & 7;
#pragma unroll
    for (int p = 0; p < 2; ++p) {
        int rl = (t >> 3) + (p << 7);           // local row 0..255
        int node = (b << CB) + rl;
        if (node >= n) continue;
        float4 va = x4[(size_t)node * 32 + l];
        float4 vb = x4[(size_t)node * 32 + l + 8];
        float4 vc = x4[(size_t)node * 32 + l + 16];
        float4 vd = x4[(size_t)node * 32 + l + 24];
        float acc[16];
#pragma unroll
        for (int j = 0; j < 16; ++j) {
            float4 wa = w4[j * 32 + l];
            float4 wb = w4[j * 32 + l + 8];
            float4 wc = w4[j * 32 + l + 16];
            float4 wd = w4[j * 32 + l + 24];
            acc[j] = va.x * wa.x + va.y * wa.y + va.z * wa.z + va.w * wa.w
                   + vb.x * wb.x + vb.y * wb.y + vb.z * wb.z + vb.w * wb.w
                   + vc.x * wc.x + vc.y * wc.y + vc.z * wc.z + vc.w * wc.w
                   + vd.x * wd.x + vd.y * wd.y + vd.z * wd.z + vd.w * wd.w;
        }
#pragma unroll
        for (int j = 0; j < 16; ++j) {
#pragma unroll
            for (int m = 4; m >= 1; m >>= 1) acc[j] += __shfl_xor(acc[j], m, 8);
        }
        float d = sdis[rl];
        __half2 hh = __floats2half2_rn(d * acc[2 * l], d * acc[2 * l + 1]);
        ((__half2*)gh)[(size_t)node * 8 + l] = hh;   // 32B coalesced
    }
}

// Unpack a 16B load (4x half2 = 8 fp16) and accumulate into 8 fp32 lanes.
__device__ inline void h8acc(float4 r, float* a) {
    const __half2* h = (const __half2*)&r;
#pragma unroll
    for (int k = 0; k < 4; ++k) {
        float2 f = __half22float2(h[k]);
        a[2 * k] += f.x;
        a[2 * k + 1] += f.y;
    }
}

// 2 threads/node, 16B (float4 = 8 fp16) reads. Width is a measured don't-care
// (R11/R15); kept at 16B.
__global__ void k_gather1(const int* __restrict__ begA, const int* __restrict__ endA,
                          const int* __restrict__ ssrc,
                          const float4* __restrict__ g8, const float* __restrict__ dis,
                          const float* __restrict__ b1, const float* __restrict__ W2,
                          float* __restrict__ tbuf, int n) {
    int t = blockIdx.x * blockDim.x + threadIdx.x;
    if (t >= n * 2) return;
    int i = t >> 1, l = t & 1;
    float di = dis[i];
    int beg = begA[i], end = endA[i];
    float a[8], b[8];                           // features 8l .. 8l+7
    {
        float4 s = g8[(size_t)i * 2 + l];       // self-loop
        const __half2* h = (const __half2*)&s;
#pragma unroll
        for (int k = 0; k < 4; ++k) {
            float2 f = __half22float2(h[k]);
            a[2 * k] = f.x;
            a[2 * k + 1] = f.y;
            b[2 * k] = 0.f;
            b[2 * k + 1] = 0.f;
        }
    }
    int e = beg;
    for (; e + 8 <= end; e += 8) {
        int s0 = ssrc[e + 0], s1 = ssrc[e + 1], s2 = ssrc[e + 2], s3 = ssrc[e + 3];
        int s4 = ssrc[e + 4], s5 = ssrc[e + 5], s6 = ssrc[e + 6], s7 = ssrc[e + 7];
        float4 r0 = g8[(size_t)s0 * 2 + l];
        float4 r1 = g8[(size_t)s1 * 2 + l];
        float4 r2 = g8[(size_t)s2 * 2 + l];
        float4 r3 = g8[(size_t)s3 * 2 + l];
        float4 r4 = g8[(size_t)s4 * 2 + l];
        float4 r5 = g8[(size_t)s5 * 2 + l];
        float4 r6 = g8[(size_t)s6 * 2 + l];
        float4 r7 = g8[(size_t)s7 * 2 + l];
        h8acc(r0, a); h8acc(r1, b);
        h8acc(r2, a); h8acc(r3, b);
        h8acc(r4, a); h8acc(r5, b);
        h8acc(r6, a); h8acc(r7, b);
    }
    for (; e < end; ++e) {
        float4 r = g8[(size_t)ssrc[e] * 2 + l];
        h8acc(r, a);
    }
    int f = l * 8;
    float u = 0.f;
#pragma unroll
    for (int k = 0; k < 8; ++k)
        u += fmaxf(di * (a[k] + b[k]) + b1[f + k], 0.f) * W2[f + k];
    u += __shfl_xor(u, 1, 2);
    if (l == 0) tbuf[i] = di * u;
}

// 8 threads/node, lane-strided edges (coalesced ssrc), unroll x4 for MLP:
// out[i] = dis[i] * (sum_e t[src] + t[i]) + b2
__global__ void k_gather2(const int* __restrict__ begA, const int* __restrict__ endA,
                          const int* __restrict__ ssrc,
                          const float* __restrict__ tbuf, const float* __restrict__ dis,
                          const float* __restrict__ b2, float* __restrict__ out, int n) {
    int t = blockIdx.x * blockDim.x + threadIdx.x;
    if (t >= n * 8) return;
    int i = t >> 3, l = t & 7;
    int beg = begA[i], end = endA[i];
    float acc = (l == 0) ? tbuf[i] : 0.f;
    float acc1 = 0.f;
    int e = beg + l;
    for (; e + 24 < end; e += 32) {
        int s0 = ssrc[e], s1 = ssrc[e + 8], s2 = ssrc[e + 16], s3 = ssrc[e + 24];
        float v0 = tbuf[s0], v1 = tbuf[s1], v2 = tbuf[s2], v3 = tbuf[s3];
        acc += v0; acc1 += v1; acc += v2; acc1 += v3;
    }
    for (; e < end; e += 8) acc += tbuf[ssrc[e]];
    acc += acc1;
#pragma unroll
    for (int m = 4; m >= 1; m >>= 1) acc += __shfl_xor(acc, m, 8);
    if (l == 0) out[i] = dis[i] * acc + b2[0];
}

extern "C" void kernel_launch(void* const* d_in, const int* in_sizes, int n_in,
                              void* d_out, int out_size, void* d_ws, size_t ws_size,
                              hipStream_t stream) {
    const float* x  = (const float*)d_in[0];
    const int*   ei = (const int*)d_in[1];
    const float* W1 = (const float*)d_in[2];
    const float* b1 = (const float*)d_in[3];
    const float* W2 = (const float*)d_in[4];
    const float* b2 = (const float*)d_in[5];
    float* out = (float*)d_out;

    const int N = in_sizes[0] / 128;   // 100000
    const int E = in_sizes[1] / 2;     // 3200000
    const int* row = ei;        // edge_index[0] = source
    const int* col = ei + E;    // edge_index[1] = target
    const int NB = (N + 255) >> CB;    // coarse buckets (391)
    const size_t PADE = (size_t)NB * CAP;  // padded edge capacity

    // workspace (4B units): ebuf[PADE] | ssrc[PADE] | dis[N] | tbuf[N] |
    // begA[N] | endA[N] | gcur[512] | gh[N*8 halfs = N*4 ints]
    // NOTE (R26): gh NO LONGER aliases ebuf — fused gemm1 writes gh while
    // other blocks still read their ebuf regions.
    int*    ebuf = (int*)d_ws;
    int*    ssrc = ebuf + PADE;
    float*  dis  = (float*)(ssrc + PADE);
    float*  tbuf = dis + N;
    int*    begA = (int*)(tbuf + N);
    int*    endA = begA + N;
    int*    gcur = endA + N;
    __half* gh   = (__half*)(gcur + 512);

    auto cdiv = [](int a, int b) { return (a + b - 1) / b; };

    k_init_gcur<<<cdiv(NB, 256),    256,  0, stream>>>(gcur, NB);
    k_partition<<<cdiv(E, TILE),    512,  0, stream>>>(row, col, gcur, ebuf, E, NB);
    k_bucket   <<<NB,               1024, 0, stream>>>(ebuf, gcur, begA, endA, ssrc, dis,
                                                       x, W1, gh, N);
    k_gather1  <<<cdiv(N * 2, 256), 256,  0, stream>>>(begA, endA, ssrc, (const float4*)gh,
                                                       dis, b1, W2, tbuf, N);
    k_gather2  <<<cdiv(N * 8, 256), 256,  0, stream>>>(begA, endA, ssrc, tbuf, dis, b2, out, N);
}